// Round 5
// baseline (326.971 us; speedup 1.0000x reference)
//
#include <hip/hip_runtime.h>

#define SEQ   2048
#define BATCH 4
#define DIM   512
#define WAVE_LDS 34816
#define ST_OFF   32768
#define NEG_INF  (-__builtin_inff())

typedef short short8 __attribute__((ext_vector_type(8)));
typedef float floatx4 __attribute__((ext_vector_type(4)));

using lds_char = __attribute__((address_space(3))) char;
using g_void   = const __attribute__((address_space(1))) void;
using l_void   = __attribute__((address_space(3))) void;

__device__ __forceinline__ short to_bf16(float x){
    unsigned u = __float_as_uint(x);
    unsigned r = (u + 0x7fffu + ((u >> 16) & 1u)) >> 16;
    return (short)r;
}

__device__ __forceinline__ short8 pack8(floatx4 a, floatx4 b, float s){
    short8 r;
    r[0]=to_bf16(a[0]*s); r[1]=to_bf16(a[1]*s); r[2]=to_bf16(a[2]*s); r[3]=to_bf16(a[3]*s);
    r[4]=to_bf16(b[0]*s); r[5]=to_bf16(b[1]*s); r[6]=to_bf16(b[2]*s); r[7]=to_bf16(b[3]*s);
    return r;
}

// K [k][b][d] fp32 -> Kimg [b][k][d] bf16 with the per-row 16B-slot XOR swizzle
// BAKED IN (slot ^= (k&7)<<3 shorts), so global_load_lds can stage linearly
// and ds_read uses the round-2-verified swizzled offsets.
extern "C" __global__ void __launch_bounds__(256)
conv_k(const float* __restrict__ K, short* __restrict__ Kimg)
{
    const int t    = blockIdx.x * 256 + threadIdx.x;   // 524288
    const int d8   = t & 63;
    const int row  = t >> 6;                           // k*BATCH + b
    const int k    = row >> 2;
    const int b    = row & 3;
    const float* src = K + (size_t)row * DIM + d8 * 8;
    floatx4 f0 = *(const floatx4*)src;
    floatx4 f1 = *(const floatx4*)(src + 4);
    const int slot = (d8 * 8) ^ ((k & 7) << 3);        // shorts
    *(short8*)(Kimg + ((size_t)b * SEQ + k) * DIM + slot) = pack8(f0, f1, 1.0f);
}

// V [k][b][dv] fp32 -> Vt [b][dv][k] bf16 (transposed, linear).
extern "C" __global__ void __launch_bounds__(256)
conv_v(const float* __restrict__ V, short* __restrict__ Vt)
{
    const int t    = blockIdx.x * 256 + threadIdx.x;   // 524288
    const int dv   = t & 511;
    const int rest = t >> 9;
    const int kc   = rest & 255;
    const int b    = rest >> 8;
    short8 colv;
    #pragma unroll
    for (int i = 0; i < 8; ++i){
        const float f = V[((size_t)(kc*8 + i) * BATCH + b) * DIM + dv];
        colv[i] = to_bf16(f);
    }
    *(short8*)(Vt + ((size_t)b * DIM + dv) * SEQ + kc * 8) = colv;
}

extern "C" __global__ void __launch_bounds__(256, 1)
fa_fwd(const float* __restrict__ Qg, const short* __restrict__ Kb,
       const short* __restrict__ Vt, const unsigned char* __restrict__ Mg,
       float* __restrict__ Og)
{
    extern __shared__ __align__(16) char smem[];
    const int tid  = threadIdx.x;
    const int w    = tid >> 6;
    const int lane = tid & 63;
    const int g    = lane >> 4;
    const int c    = lane & 15;

    // XCD-affine swizzle: batch pinned to an XCD pair for KV L2 locality.
    const int x    = blockIdx.x;
    const int slot = x & 7;
    const int idx  = x >> 3;
    const int b    = slot >> 1;
    const int qt   = idx * 2 + (slot & 1);

    const int qhalf = w & 1;
    const int par   = w >> 1;
    const int q0    = qt * 32 + qhalf * 16;

    char* wbase = smem + w * WAVE_LDS;
    char* tile  = wbase;              // 32KB staged K tile (swizzled image)
    char* Pb    = wbase + ST_OFF;     // P (1KB) during loop; stats (2KB) after

    const short* Kbb = Kb + (size_t)b * SEQ * DIM;
    const short* Vtb = Vt + (size_t)b * DIM * SEQ;

    // ---- Q -> registers (bf16, pre-scaled by 1/sqrt(D)) ----
    const float scale = 0.04419417382415922f;  // 1/sqrt(512)
    short8 qreg[16];
    {
        const float* qrow = Qg + ((size_t)(q0 + c) * BATCH + b) * DIM + g * 8;
        #pragma unroll
        for (int ks = 0; ks < 16; ++ks){
            floatx4 f0 = *(const floatx4*)(qrow + ks*32);
            floatx4 f1 = *(const floatx4*)(qrow + ks*32 + 4);
            qreg[ks] = pack8(f0, f1, scale);
        }
    }

    floatx4 oacc[32];
    #pragma unroll
    for (int i=0;i<32;++i){ floatx4 z = {0.f,0.f,0.f,0.f}; oacc[i]=z; }
    float mrow[4] = {NEG_INF, NEG_INF, NEG_INF, NEG_INF};
    float lrow[4] = {0.f,0.f,0.f,0.f};

    const int ntiles = ((q0 + 15) >> 5) + 1;   // causal: kv tiles 0..qt

    // bulk async stage of one 32-row K tile (32 KB) into this wave's buffer
    #define STAGE_K(tt) { \
        const short* ksrc_ = Kbb + (size_t)((tt)*32) * DIM + lane*8; \
        _Pragma("unroll") \
        for (int i_ = 0; i_ < 32; ++i_){ \
            __builtin_amdgcn_global_load_lds((g_void*)(ksrc_ + (size_t)i_*DIM), \
                                             (l_void*)(lds_char*)(tile + i_*1024), 16, 0, 0); \
        } }

    if (par < ntiles) STAGE_K(par);

    for (int t = par; t < ntiles; t += 2){
        const int kb = t * 32;

        // staged K(t) must have landed
        asm volatile("s_waitcnt vmcnt(0)" ::: "memory");
        __builtin_amdgcn_sched_barrier(0);

        // mask bytes early (tiny, won't force a late queue drain)
        const unsigned char km0 = Mg[(kb + c) * BATCH + b];
        const unsigned char km1 = Mg[(kb + 16 + c) * BATCH + b];

        // ---- S = Q K^T (A=Q regs, B=K from LDS, verified swizzled reads) ----
        floatx4 sacc[2];
        { floatx4 z = {0.f,0.f,0.f,0.f}; sacc[0]=z; sacc[1]=z; }
        #pragma unroll
        for (int ks = 0; ks < 16; ++ks){
            #pragma unroll
            for (int nt = 0; nt < 2; ++nt){
                const int kcol = nt*16 + c;
                short8 kf = *(const short8*)(tile + kcol*1024 +
                               ((ks*64 + g*16) ^ ((kcol & 7) << 4)));
                sacc[nt] = __builtin_amdgcn_mfma_f32_16x16x32_bf16(qreg[ks], kf, sacc[nt], 0,0,0);
            }
        }

        // drain LDS reads, then prefetch K(t+2) under softmax+PV
        asm volatile("s_waitcnt lgkmcnt(0)" ::: "memory");
        __builtin_amdgcn_sched_barrier(0);
        if (t + 2 < ntiles) STAGE_K(t + 2);

        // ---- issue ALL V fragment loads now; softmax hides their latency ----
        short8 vf[32];
        #pragma unroll
        for (int nt = 0; nt < 32; ++nt){
            const int dv = nt*16 + c;
            vf[nt] = *(const short8*)(Vtb + (size_t)dv * SEQ + kb + g*8);
        }

        // ---- masks + online softmax (C layout: row=g*4+jj, col=nt*16+c) ----
        float s[2][4];
        #pragma unroll
        for (int nt = 0; nt < 2; ++nt){
            const int col = kb + nt*16 + c;
            const unsigned char km = nt ? km1 : km0;
            #pragma unroll
            for (int jj = 0; jj < 4; ++jj){
                const int row = q0 + g*4 + jj;
                s[nt][jj] = (col > row || km) ? NEG_INF : sacc[nt][jj];
            }
        }
        float pmax[4];
        #pragma unroll
        for (int jj=0;jj<4;++jj) pmax[jj] = fmaxf(s[0][jj], s[1][jj]);
        #pragma unroll
        for (int msk=1; msk<16; msk<<=1){
            #pragma unroll
            for (int jj=0;jj<4;++jj)
                pmax[jj] = fmaxf(pmax[jj], __shfl_xor(pmax[jj], msk, 64));
        }
        const bool okd = (pmax[0] <= mrow[0]+8.f) && (pmax[1] <= mrow[1]+8.f)
                      && (pmax[2] <= mrow[2]+8.f) && (pmax[3] <= mrow[3]+8.f);
        if (!__all(okd)){
            float fsc[4];
            #pragma unroll
            for (int jj=0;jj<4;++jj){
                const float M = fmaxf(mrow[jj], pmax[jj]);
                const float f = (mrow[jj] == NEG_INF) ? 0.f : __expf(mrow[jj] - M);
                mrow[jj] = M; lrow[jj] *= f; fsc[jj] = f;
            }
            #pragma unroll
            for (int nt=0; nt<32; ++nt){
                #pragma unroll
                for (int jj=0; jj<4; ++jj) oacc[nt][jj] *= fsc[jj];
            }
        }
        float parr[2][4], psum[4] = {0.f,0.f,0.f,0.f};
        #pragma unroll
        for (int nt=0; nt<2; ++nt){
            #pragma unroll
            for (int jj=0; jj<4; ++jj){
                const float sv = s[nt][jj];
                const float e = (sv == NEG_INF) ? 0.f : __expf(sv - mrow[jj]);
                parr[nt][jj] = e; psum[jj] += e;
            }
        }
        #pragma unroll
        for (int msk=1; msk<16; msk<<=1){
            #pragma unroll
            for (int jj=0;jj<4;++jj) psum[jj] += __shfl_xor(psum[jj], msk, 64);
        }
        #pragma unroll
        for (int jj=0;jj<4;++jj) lrow[jj] += psum[jj];

        // ---- P as [q=16][k=32] bf16 row-major in LDS (verified layout) ----
        #pragma unroll
        for (int nt=0; nt<2; ++nt){
            #pragma unroll
            for (int jj=0; jj<4; ++jj){
                *(short*)(Pb + (g*4 + jj)*64 + (nt*16 + c)*2) = to_bf16(parr[nt][jj]);
            }
        }

        // ---- O += P V : A = P (LDS b128), B = vf already in registers ----
        const short8 pfrag = *(const short8*)(Pb + c*64 + g*16);
        #pragma unroll
        for (int nt = 0; nt < 32; ++nt){
            oacc[nt] = __builtin_amdgcn_mfma_f32_16x16x32_bf16(pfrag, vf[nt], oacc[nt], 0,0,0);
        }
    }
    #undef STAGE_K

    // ---- merge kv-parity partials: waves (0,2) and (1,3) share q rows ----
    __syncthreads();
    if (par == 1){
        float* ox = (float*)tile;          // 32KB lane-linear dump
        #pragma unroll
        for (int nt=0; nt<32; ++nt){
            #pragma unroll
            for (int jj=0; jj<4; ++jj) ox[(nt*4 + jj)*64 + lane] = oacc[nt][jj];
        }
        float* st = (float*)(wbase + ST_OFF);
        #pragma unroll
        for (int jj=0; jj<4; ++jj){ st[jj*64 + lane] = mrow[jj]; st[(4+jj)*64 + lane] = lrow[jj]; }
    }
    __syncthreads();
    if (par == 0){
        char* pbase2 = smem + (w + 2) * WAVE_LDS;
        const float* ox = (const float*)pbase2;
        const float* st = (const float*)(pbase2 + ST_OFF);
        #pragma unroll
        for (int jj=0; jj<4; ++jj){
            const float m2 = st[jj*64 + lane];
            const float l2 = st[(4+jj)*64 + lane];
            const float M  = fmaxf(mrow[jj], m2);
            const float a1 = (mrow[jj] == NEG_INF) ? 0.f : __expf(mrow[jj] - M);
            const float a2 = (m2       == NEG_INF) ? 0.f : __expf(m2 - M);
            const float L  = a1*lrow[jj] + a2*l2;
            const float inv = 1.0f / L;
            float* orow = Og + ((size_t)(q0 + g*4 + jj) * BATCH + b) * DIM + c;
            #pragma unroll
            for (int nt=0; nt<32; ++nt){
                const float o2 = ox[(nt*4 + jj)*64 + lane];
                orow[nt*16] = (a1*oacc[nt][jj] + a2*o2) * inv;
            }
        }
    }
}

extern "C" void kernel_launch(void* const* d_in, const int* in_sizes, int n_in,
                              void* d_out, int out_size, void* d_ws, size_t ws_size,
                              hipStream_t stream)
{
    const float* Q = (const float*)d_in[0];
    const float* K = (const float*)d_in[1];
    const float* V = (const float*)d_in[2];
    const unsigned char* M = (const unsigned char*)d_in[3];
    float* O = (float*)d_out;
    (void)in_sizes; (void)n_in; (void)out_size; (void)ws_size;

    short* Kb = (short*)d_ws;                               // 8.4 MB swizzled image
    short* Vt = Kb + (size_t)BATCH * SEQ * DIM;             // 8.4 MB V^T

    conv_k<<<2048, 256, 0, stream>>>(K, Kb);
    conv_v<<<2048, 256, 0, stream>>>(V, Vt);

    hipFuncSetAttribute(reinterpret_cast<const void*>(fa_fwd),
                        hipFuncAttributeMaxDynamicSharedMemorySize, 4*WAVE_LDS);
    fa_fwd<<<256, 256, 4*WAVE_LDS, stream>>>(Q, Kb, Vt, M, O);
}

// Round 6
// 240.371 us; speedup vs baseline: 1.3603x; 1.3603x over previous
//
#include <hip/hip_runtime.h>

#define SEQ   2048
#define BATCH 4
#define DIM   512
#define KBUF  32768
#define P_AREA 131072
#define STAT_AREA 139264
#define LDS_TOTAL 155648
#define NEG_INF  (-__builtin_inff())

typedef short short8 __attribute__((ext_vector_type(8)));
typedef float floatx4 __attribute__((ext_vector_type(4)));

using lds_char = __attribute__((address_space(3))) char;
using g_void   = const __attribute__((address_space(1))) void;
using l_void   = __attribute__((address_space(3))) void;

__device__ __forceinline__ short to_bf16(float x){
    unsigned u = __float_as_uint(x);
    unsigned r = (u + 0x7fffu + ((u >> 16) & 1u)) >> 16;
    return (short)r;
}

__device__ __forceinline__ short8 pack8(floatx4 a, floatx4 b, float s){
    short8 r;
    r[0]=to_bf16(a[0]*s); r[1]=to_bf16(a[1]*s); r[2]=to_bf16(a[2]*s); r[3]=to_bf16(a[3]*s);
    r[4]=to_bf16(b[0]*s); r[5]=to_bf16(b[1]*s); r[6]=to_bf16(b[2]*s); r[7]=to_bf16(b[3]*s);
    return r;
}

// K [k][b][d] fp32 -> Kimg [b][k][d] bf16 with per-row 16B-slot XOR swizzle
// baked in (slot ^= (k&7)<<3 shorts) so global_load_lds stages linearly and
// ds_read uses the validated swizzled offsets.
extern "C" __global__ void __launch_bounds__(256)
conv_k(const float* __restrict__ K, short* __restrict__ Kimg)
{
    const int t    = blockIdx.x * 256 + threadIdx.x;   // 524288
    const int d8   = t & 63;
    const int row  = t >> 6;                           // k*BATCH + b
    const int k    = row >> 2;
    const int b    = row & 3;
    const float* src = K + (size_t)row * DIM + d8 * 8;
    floatx4 f0 = *(const floatx4*)src;
    floatx4 f1 = *(const floatx4*)(src + 4);
    const int slot = (d8 * 8) ^ ((k & 7) << 3);        // shorts
    *(short8*)(Kimg + ((size_t)b * SEQ + k) * DIM + slot) = pack8(f0, f1, 1.0f);
}

// V [k][b][dv] fp32 -> Vt [b][dv][k] bf16 (transposed, linear).
extern "C" __global__ void __launch_bounds__(256)
conv_v(const float* __restrict__ V, short* __restrict__ Vt)
{
    const int t    = blockIdx.x * 256 + threadIdx.x;   // 524288
    const int dv   = t & 511;
    const int rest = t >> 9;
    const int kc   = rest & 255;
    const int b    = rest >> 8;
    short8 colv;
    #pragma unroll
    for (int i = 0; i < 8; ++i){
        const float f = V[((size_t)(kc*8 + i) * BATCH + b) * DIM + dv];
        colv[i] = to_bf16(f);
    }
    *(short8*)(Vt + ((size_t)b * DIM + dv) * SEQ + kc * 8) = colv;
}

__device__ __forceinline__ void dump_partial(float* ox, float* st,
    const floatx4* oacc, const float* mrow, const float* lrow, int lane)
{
    #pragma unroll
    for (int nt=0; nt<32; ++nt){
        #pragma unroll
        for (int jj=0; jj<4; ++jj) ox[(nt*4 + jj)*64 + lane] = oacc[nt][jj];
    }
    #pragma unroll
    for (int jj=0; jj<4; ++jj){ st[jj*64 + lane] = mrow[jj]; st[(4+jj)*64 + lane] = lrow[jj]; }
}

__device__ __forceinline__ void combine_partial(floatx4* oacc, float* mrow, float* lrow,
    const float* ox, const float* st, int lane)
{
    #pragma unroll
    for (int jj=0; jj<4; ++jj){
        const float m2 = st[jj*64 + lane];
        const float l2 = st[(4+jj)*64 + lane];
        const float M  = fmaxf(mrow[jj], m2);
        const float a1 = (mrow[jj] == NEG_INF) ? 0.f : __expf(mrow[jj] - M);
        const float a2 = (m2       == NEG_INF) ? 0.f : __expf(m2 - M);
        mrow[jj] = M;
        lrow[jj] = a1*lrow[jj] + a2*l2;
        #pragma unroll
        for (int nt=0; nt<32; ++nt)
            oacc[nt][jj] = a1*oacc[nt][jj] + a2*ox[(nt*4 + jj)*64 + lane];
    }
}

extern "C" __global__ void __launch_bounds__(512, 2)
fa_fwd(const float* __restrict__ Qg, const short* __restrict__ Kb,
       const short* __restrict__ Vt, const unsigned char* __restrict__ Mg,
       float* __restrict__ Og)
{
    extern __shared__ __align__(16) char smem[];
    const int tid  = threadIdx.x;
    const int w    = tid >> 6;        // 0..7
    const int lane = tid & 63;
    const int g    = lane >> 4;
    const int c    = lane & 15;
    const int qhalf = w & 1;
    const int par   = w >> 1;         // 4-way kv split

    // XCD-affine swizzle: batch pinned to an XCD pair for KV L2 locality.
    const int x    = blockIdx.x;
    const int slot = x & 7;
    const int idx  = x >> 3;
    const int b    = slot >> 1;
    const int qt   = idx * 2 + (slot & 1);   // 0..63

    const int q0 = qt * 32 + qhalf * 16;

    char* kbuf = smem + par * KBUF;          // shared by both qhalf waves of this parity
    char* Pb   = smem + P_AREA + w * 1024;

    const short* Kbb = Kb + (size_t)b * SEQ * DIM;
    const short* Vtb = Vt + (size_t)b * DIM * SEQ;

    // ---- Q -> registers (bf16, pre-scaled by 1/sqrt(D)) ----
    const float scale = 0.04419417382415922f;  // 1/sqrt(512)
    short8 qreg[16];
    {
        const float* qrow = Qg + ((size_t)(q0 + c) * BATCH + b) * DIM + g * 8;
        #pragma unroll
        for (int ks = 0; ks < 16; ++ks){
            floatx4 f0 = *(const floatx4*)(qrow + ks*32);
            floatx4 f1 = *(const floatx4*)(qrow + ks*32 + 4);
            qreg[ks] = pack8(f0, f1, scale);
        }
    }

    floatx4 oacc[32];
    #pragma unroll
    for (int i=0;i<32;++i){ floatx4 z = {0.f,0.f,0.f,0.f}; oacc[i]=z; }
    float mrow[4] = {NEG_INF, NEG_INF, NEG_INF, NEG_INF};
    float lrow[4] = {0.f,0.f,0.f,0.f};

    const int ntiles = qt + 1;               // uniform across the block
    const int iters  = (ntiles + 3) >> 2;

    // wave stages its 16 rows of the parity-pair's 32-row K tile
    #define STAGE_K(tt) { \
        const short* ksrc_ = Kbb + ((size_t)((tt)*32 + qhalf*16)) * DIM + lane*8; \
        char* ldst_ = kbuf + qhalf*16*1024; \
        _Pragma("unroll") \
        for (int i_ = 0; i_ < 16; ++i_) \
            __builtin_amdgcn_global_load_lds((g_void*)(ksrc_ + (size_t)i_*DIM), \
                                             (l_void*)(lds_char*)(ldst_ + i_*1024), 16, 0, 0); }

    if (par < ntiles) STAGE_K(par);

    for (int i = 0; i < iters; ++i){
        const int t  = 4*i + par;
        const int kb = t * 32;
        const bool active = (t < ntiles);

        __syncthreads();   // [A] staged K visible to both qhalf waves

        floatx4 sacc[2];
        { floatx4 z = {0.f,0.f,0.f,0.f}; sacc[0]=z; sacc[1]=z; }
        unsigned char km0 = 0, km1 = 0;
        if (active){
            km0 = Mg[(kb + c) * BATCH + b];
            km1 = Mg[(kb + 16 + c) * BATCH + b];
            #pragma unroll
            for (int ks = 0; ks < 16; ++ks){
                #pragma unroll
                for (int nt = 0; nt < 2; ++nt){
                    const int kcol = nt*16 + c;
                    short8 kf = *(const short8*)(kbuf + kcol*1024 +
                                   ((ks*64 + g*16) ^ ((kcol & 7) << 4)));
                    sacc[nt] = __builtin_amdgcn_mfma_f32_16x16x32_bf16(qreg[ks], kf, sacc[nt], 0,0,0);
                }
            }
        }

        __syncthreads();   // [B] all reads of kbuf done -> safe to restage

        if (t + 4 < ntiles) STAGE_K(t + 4);

        if (active){
            // ---- masks + online softmax (C layout: row=g*4+jj, col=nt*16+c) ----
            float s[2][4];
            #pragma unroll
            for (int nt = 0; nt < 2; ++nt){
                const int col = kb + nt*16 + c;
                const unsigned char km = nt ? km1 : km0;
                #pragma unroll
                for (int jj = 0; jj < 4; ++jj){
                    const int row = q0 + g*4 + jj;
                    s[nt][jj] = (col > row || km) ? NEG_INF : sacc[nt][jj];
                }
            }
            float pmax[4];
            #pragma unroll
            for (int jj=0;jj<4;++jj) pmax[jj] = fmaxf(s[0][jj], s[1][jj]);
            #pragma unroll
            for (int msk=1; msk<16; msk<<=1){
                #pragma unroll
                for (int jj=0;jj<4;++jj)
                    pmax[jj] = fmaxf(pmax[jj], __shfl_xor(pmax[jj], msk, 64));
            }
            const bool okd = (pmax[0] <= mrow[0]+8.f) && (pmax[1] <= mrow[1]+8.f)
                          && (pmax[2] <= mrow[2]+8.f) && (pmax[3] <= mrow[3]+8.f);
            if (!__all(okd)){
                float fsc[4];
                #pragma unroll
                for (int jj=0;jj<4;++jj){
                    const float M = fmaxf(mrow[jj], pmax[jj]);
                    const float f = (mrow[jj] == NEG_INF) ? 0.f : __expf(mrow[jj] - M);
                    mrow[jj] = M; lrow[jj] *= f; fsc[jj] = f;
                }
                #pragma unroll
                for (int nt=0; nt<32; ++nt){
                    #pragma unroll
                    for (int jj=0; jj<4; ++jj) oacc[nt][jj] *= fsc[jj];
                }
            }
            float parr[2][4], psum[4] = {0.f,0.f,0.f,0.f};
            #pragma unroll
            for (int nt=0; nt<2; ++nt){
                #pragma unroll
                for (int jj=0; jj<4; ++jj){
                    const float sv = s[nt][jj];
                    const float e = (sv == NEG_INF) ? 0.f : __expf(sv - mrow[jj]);
                    parr[nt][jj] = e; psum[jj] += e;
                }
            }
            #pragma unroll
            for (int msk=1; msk<16; msk<<=1){
                #pragma unroll
                for (int jj=0;jj<4;++jj) psum[jj] += __shfl_xor(psum[jj], msk, 64);
            }
            #pragma unroll
            for (int jj=0;jj<4;++jj) lrow[jj] += psum[jj];

            // ---- P as [q=16][k=32] bf16 row-major in per-wave LDS ----
            #pragma unroll
            for (int nt=0; nt<2; ++nt){
                #pragma unroll
                for (int jj=0; jj<4; ++jj){
                    *(short*)(Pb + (g*4 + jj)*64 + (nt*16 + c)*2) = to_bf16(parr[nt][jj]);
                }
            }

            // ---- O += P V : A = P (LDS b128), B = V^T direct from L2 ----
            const short8 pfrag = *(const short8*)(Pb + c*64 + g*16);
            #pragma unroll
            for (int nt = 0; nt < 32; ++nt){
                const short8 vfr = *(const short8*)(Vtb + (size_t)(nt*16 + c) * SEQ + kb + g*8);
                oacc[nt] = __builtin_amdgcn_mfma_f32_16x16x32_bf16(pfrag, vfr, oacc[nt], 0,0,0);
            }
        }
    }
    #undef STAGE_K

    // ---- 2-round tree merge of the 4 kv-parity partials (per qhalf) ----
    float* stme = (float*)(smem + STAT_AREA + w * 2048);

    __syncthreads();
    if (par & 1){    // par 1 -> slot qhalf ; par 3 -> slot 2+qhalf
        float* ox = (float*)(smem + ((par >> 1)*2 + qhalf) * KBUF);
        dump_partial(ox, stme, oacc, mrow, lrow, lane);
    }
    __syncthreads();
    if (!(par & 1)){
        const float* ox = (const float*)(smem + ((par >> 1)*2 + qhalf) * KBUF);
        const float* st = (const float*)(smem + STAT_AREA + (w + 2) * 2048);
        combine_partial(oacc, mrow, lrow, ox, st, lane);
    }
    __syncthreads();
    if (par == 2){
        float* ox = (float*)(smem + (2 + qhalf) * KBUF);
        dump_partial(ox, stme, oacc, mrow, lrow, lane);
    }
    __syncthreads();
    if (par == 0){
        const float* ox = (const float*)(smem + (2 + qhalf) * KBUF);
        const float* st = (const float*)(smem + STAT_AREA + (w + 4) * 2048);
        combine_partial(oacc, mrow, lrow, ox, st, lane);
        #pragma unroll
        for (int jj=0; jj<4; ++jj){
            const float inv = 1.0f / lrow[jj];
            float* orow = Og + ((size_t)(q0 + g*4 + jj) * BATCH + b) * DIM + c;
            #pragma unroll
            for (int nt=0; nt<32; ++nt) orow[nt*16] = oacc[nt][jj] * inv;
        }
    }
}

extern "C" void kernel_launch(void* const* d_in, const int* in_sizes, int n_in,
                              void* d_out, int out_size, void* d_ws, size_t ws_size,
                              hipStream_t stream)
{
    const float* Q = (const float*)d_in[0];
    const float* K = (const float*)d_in[1];
    const float* V = (const float*)d_in[2];
    const unsigned char* M = (const unsigned char*)d_in[3];
    float* O = (float*)d_out;
    (void)in_sizes; (void)n_in; (void)out_size; (void)ws_size;

    short* Kb = (short*)d_ws;                               // 8.4 MB swizzled image
    short* Vt = Kb + (size_t)BATCH * SEQ * DIM;             // 8.4 MB V^T

    conv_k<<<2048, 256, 0, stream>>>(K, Kb);
    conv_v<<<2048, 256, 0, stream>>>(V, Vt);

    hipFuncSetAttribute(reinterpret_cast<const void*>(fa_fwd),
                        hipFuncAttributeMaxDynamicSharedMemorySize, LDS_TOTAL);
    fa_fwd<<<256, 512, LDS_TOTAL, stream>>>(Q, Kb, Vt, M, O);
}

// Round 8
// 139.613 us; speedup vs baseline: 2.3420x; 1.7217x over previous
//
#include <hip/hip_runtime.h>

#define SEQ   2048
#define BATCH 4
#define DIM   512
#define KBUF  32768
#define P_AREA 131072
#define STAT_AREA 139264
#define LDS_TOTAL 155648
#define NEG_INF  (-__builtin_inff())

typedef short short8 __attribute__((ext_vector_type(8)));
typedef float floatx4 __attribute__((ext_vector_type(4)));

using lds_char = __attribute__((address_space(3))) char;
using g_void   = const __attribute__((address_space(1))) void;
using l_void   = __attribute__((address_space(3))) void;

__device__ __forceinline__ short to_bf16(float x){
    unsigned u = __float_as_uint(x);
    unsigned r = (u + 0x7fffu + ((u >> 16) & 1u)) >> 16;
    return (short)r;
}

__device__ __forceinline__ short8 pack8(floatx4 a, floatx4 b, float s){
    short8 r;
    r[0]=to_bf16(a[0]*s); r[1]=to_bf16(a[1]*s); r[2]=to_bf16(a[2]*s); r[3]=to_bf16(a[3]*s);
    r[4]=to_bf16(b[0]*s); r[5]=to_bf16(b[1]*s); r[6]=to_bf16(b[2]*s); r[7]=to_bf16(b[3]*s);
    return r;
}

// K [k][b][d] fp32 -> Kimg [b][k][d] bf16, per-row 16B-slot XOR swizzle baked in.
extern "C" __global__ void __launch_bounds__(256)
conv_k(const float* __restrict__ K, short* __restrict__ Kimg)
{
    const int t    = blockIdx.x * 256 + threadIdx.x;   // 524288
    const int d8   = t & 63;
    const int row  = t >> 6;                           // k*BATCH + b
    const int k    = row >> 2;
    const int b    = row & 3;
    const float* src = K + (size_t)row * DIM + d8 * 8;
    floatx4 f0 = *(const floatx4*)src;
    floatx4 f1 = *(const floatx4*)(src + 4);
    const int slot = (d8 * 8) ^ ((k & 7) << 3);        // shorts
    *(short8*)(Kimg + ((size_t)b * SEQ + k) * DIM + slot) = pack8(f0, f1, 1.0f);
}

// V [k][b][dv] fp32 -> Vt [b][dv][k] bf16 (transposed, LINEAR — round-6 verified).
extern "C" __global__ void __launch_bounds__(256)
conv_v(const float* __restrict__ V, short* __restrict__ Vt)
{
    const int t    = blockIdx.x * 256 + threadIdx.x;   // 524288
    const int dv   = t & 511;
    const int rest = t >> 9;
    const int kc   = rest & 255;
    const int b    = rest >> 8;
    short8 colv;
    #pragma unroll
    for (int i = 0; i < 8; ++i){
        const float f = V[((size_t)(kc*8 + i) * BATCH + b) * DIM + dv];
        colv[i] = to_bf16(f);
    }
    *(short8*)(Vt + ((size_t)b * DIM + dv) * SEQ + kc * 8) = colv;
}

__device__ __forceinline__ void dump_partial(float* ox, float* st,
    const floatx4* oacc, const float* mrow, const float* lrow, int lane)
{
    #pragma unroll
    for (int nt=0; nt<32; ++nt){
        #pragma unroll
        for (int jj=0; jj<4; ++jj) ox[(nt*4 + jj)*64 + lane] = oacc[nt][jj];
    }
    #pragma unroll
    for (int jj=0; jj<4; ++jj){ st[jj*64 + lane] = mrow[jj]; st[(4+jj)*64 + lane] = lrow[jj]; }
}

__device__ __forceinline__ void combine_partial(floatx4* oacc, float* mrow, float* lrow,
    const float* ox, const float* st, int lane)
{
    #pragma unroll
    for (int jj=0; jj<4; ++jj){
        const float m2 = st[jj*64 + lane];
        const float l2 = st[(4+jj)*64 + lane];
        const float M  = fmaxf(mrow[jj], m2);
        const float a1 = (mrow[jj] == NEG_INF) ? 0.f : __expf(mrow[jj] - M);
        const float a2 = (m2       == NEG_INF) ? 0.f : __expf(m2 - M);
        mrow[jj] = M;
        lrow[jj] = a1*lrow[jj] + a2*l2;
        #pragma unroll
        for (int nt=0; nt<32; ++nt)
            oacc[nt][jj] = a1*oacc[nt][jj] + a2*ox[(nt*4 + jj)*64 + lane];
    }
}

extern "C" __global__ void __launch_bounds__(512, 2)
fa_fwd(const float* __restrict__ Qg, const short* __restrict__ Kb,
       const short* __restrict__ Vt, const unsigned char* __restrict__ Mg,
       float* __restrict__ Og)
{
    extern __shared__ __align__(16) char smem[];
    const int tid  = threadIdx.x;
    const int w    = tid >> 6;        // 0..7
    const int lane = tid & 63;
    const int g    = lane >> 4;
    const int c    = lane & 15;
    const int qhalf = w & 1;
    const int par   = w >> 1;         // 4-way kv split

    // XCD-affine swizzle: batch pinned to an XCD pair for KV L2 locality.
    const int x    = blockIdx.x;
    const int slot = x & 7;
    const int idx  = x >> 3;
    const int b    = slot >> 1;
    const int qt   = idx * 2 + (slot & 1);   // 0..63

    const int q0 = qt * 32 + qhalf * 16;

    char* kbuf = smem + par * KBUF;          // K(t) then V(t), per parity pair
    char* Pb   = smem + P_AREA + w * 1024;

    const short* Kbb = Kb + (size_t)b * SEQ * DIM;
    const short* Vtb = Vt + (size_t)b * DIM * SEQ;

    // ---- Q -> registers (bf16, pre-scaled by 1/sqrt(D)) ----
    const float scale = 0.04419417382415922f;  // 1/sqrt(512)
    short8 qreg[16];
    {
        const float* qrow = Qg + ((size_t)(q0 + c) * BATCH + b) * DIM + g * 8;
        #pragma unroll
        for (int ks = 0; ks < 16; ++ks){
            floatx4 f0 = *(const floatx4*)(qrow + ks*32);
            floatx4 f1 = *(const floatx4*)(qrow + ks*32 + 4);
            qreg[ks] = pack8(f0, f1, scale);
        }
    }

    floatx4 oacc[32];
    #pragma unroll
    for (int i=0;i<32;++i){ floatx4 z = {0.f,0.f,0.f,0.f}; oacc[i]=z; }
    float mrow[4] = {NEG_INF, NEG_INF, NEG_INF, NEG_INF};
    float lrow[4] = {0.f,0.f,0.f,0.f};

    const int ntiles = qt + 1;               // uniform across the block
    const int iters  = (ntiles + 3) >> 2;

    // wave stages its 16 rows of the parity pair's 32-row K tile (16KB)
    #define STAGE_K(tt) { \
        const short* ksrc_ = Kbb + ((size_t)((tt)*32 + qhalf*16)) * DIM + lane*8; \
        char* ldst_ = kbuf + qhalf*16384; \
        _Pragma("unroll") \
        for (int i_ = 0; i_ < 16; ++i_) \
            __builtin_amdgcn_global_load_lds((g_void*)(ksrc_ + (size_t)i_*DIM), \
                                             (l_void*)(lds_char*)(ldst_ + i_*1024), 16, 0, 0); }

    // wave stages its 256 dv-rows of the V tile from the LINEAR [dv][k] image,
    // pre-swizzling the per-lane SOURCE so the linear LDS dest ends up with
    // slot s holding chunk s ^ ((dv>>2)&3)  (m173 pattern: swizzle source, not dest)
    #define STAGE_V(tt) { \
        const int dvr_ = qhalf*256 + (lane >> 2); \
        const int q8_  = (lane & 3) ^ (lane >> 4); \
        const short* vsrc_ = Vtb + (size_t)dvr_*SEQ + (tt)*32 + q8_*8; \
        char* ldst_ = kbuf + qhalf*16384 + (lane & 3)*0; \
        _Pragma("unroll") \
        for (int i_ = 0; i_ < 16; ++i_) \
            __builtin_amdgcn_global_load_lds((g_void*)(vsrc_ + (size_t)i_*16*SEQ), \
                                             (l_void*)(lds_char*)(ldst_ + i_*1024), 16, 0, 0); }

    if (par < ntiles) STAGE_K(par);

    for (int i = 0; i < iters; ++i){
        const int t  = 4*i + par;
        const int kb = t * 32;
        const bool active = (t < ntiles);

        asm volatile("s_waitcnt vmcnt(0)" ::: "memory");
        __syncthreads();   // [A] K(t) staged & visible

        floatx4 sacc[2];
        { floatx4 z = {0.f,0.f,0.f,0.f}; sacc[0]=z; sacc[1]=z; }
        unsigned char km0 = 0, km1 = 0;
        if (active){
            km0 = Mg[(kb + c) * BATCH + b];
            km1 = Mg[(kb + 16 + c) * BATCH + b];
            #pragma unroll
            for (int ks = 0; ks < 16; ++ks){
                #pragma unroll
                for (int nt = 0; nt < 2; ++nt){
                    const int kcol = nt*16 + c;
                    short8 kf = *(const short8*)(kbuf + kcol*1024 +
                                   ((ks*64 + g*16) ^ ((kcol & 7) << 4)));
                    sacc[nt] = __builtin_amdgcn_mfma_f32_16x16x32_bf16(qreg[ks], kf, sacc[nt], 0,0,0);
                }
            }
        }

        __syncthreads();   // [B] K reads done -> kbuf reusable for V

        if (active) STAGE_V(t);

        if (active){
            // ---- masks + online softmax (C layout: row=g*4+jj, col=nt*16+c) ----
            float s[2][4];
            #pragma unroll
            for (int nt = 0; nt < 2; ++nt){
                const int col = kb + nt*16 + c;
                const unsigned char km = nt ? km1 : km0;
                #pragma unroll
                for (int jj = 0; jj < 4; ++jj){
                    const int row = q0 + g*4 + jj;
                    s[nt][jj] = (col > row || km) ? NEG_INF : sacc[nt][jj];
                }
            }
            float pmax[4];
            #pragma unroll
            for (int jj=0;jj<4;++jj) pmax[jj] = fmaxf(s[0][jj], s[1][jj]);
            #pragma unroll
            for (int msk=1; msk<16; msk<<=1){
                #pragma unroll
                for (int jj=0;jj<4;++jj)
                    pmax[jj] = fmaxf(pmax[jj], __shfl_xor(pmax[jj], msk, 64));
            }
            const bool okd = (pmax[0] <= mrow[0]+8.f) && (pmax[1] <= mrow[1]+8.f)
                          && (pmax[2] <= mrow[2]+8.f) && (pmax[3] <= mrow[3]+8.f);
            if (!__all(okd)){
                float fsc[4];
                #pragma unroll
                for (int jj=0;jj<4;++jj){
                    const float M = fmaxf(mrow[jj], pmax[jj]);
                    const float f = (mrow[jj] == NEG_INF) ? 0.f : __expf(mrow[jj] - M);
                    mrow[jj] = M; lrow[jj] *= f; fsc[jj] = f;
                }
                #pragma unroll
                for (int nt=0; nt<32; ++nt){
                    #pragma unroll
                    for (int jj=0; jj<4; ++jj) oacc[nt][jj] *= fsc[jj];
                }
            }
            float parr[2][4], psum[4] = {0.f,0.f,0.f,0.f};
            #pragma unroll
            for (int nt=0; nt<2; ++nt){
                #pragma unroll
                for (int jj=0; jj<4; ++jj){
                    const float sv = s[nt][jj];
                    const float e = (sv == NEG_INF) ? 0.f : __expf(sv - mrow[jj]);
                    parr[nt][jj] = e; psum[jj] += e;
                }
            }
            #pragma unroll
            for (int msk=1; msk<16; msk<<=1){
                #pragma unroll
                for (int jj=0;jj<4;++jj) psum[jj] += __shfl_xor(psum[jj], msk, 64);
            }
            #pragma unroll
            for (int jj=0;jj<4;++jj) lrow[jj] += psum[jj];

            // ---- P as [q=16][k=32] bf16 row-major in per-wave LDS ----
            #pragma unroll
            for (int nt=0; nt<2; ++nt){
                #pragma unroll
                for (int jj=0; jj<4; ++jj){
                    *(short*)(Pb + (g*4 + jj)*64 + (nt*16 + c)*2) = to_bf16(parr[nt][jj]);
                }
            }
        }

        asm volatile("s_waitcnt vmcnt(0)" ::: "memory");
        __syncthreads();   // [C] V(t) staged & visible

        if (active){
            // ---- O += P V : A = P (LDS b128), B = V from LDS (slot^key swz) ----
            const short8 pfrag = *(const short8*)(Pb + c*64 + g*16);
            #pragma unroll
            for (int nt = 0; nt < 32; ++nt){
                const int dv = nt*16 + c;
                const short8 vfr = *(const short8*)(kbuf + dv*64 +
                                      ((g ^ ((dv >> 2) & 3)) << 4));
                oacc[nt] = __builtin_amdgcn_mfma_f32_16x16x32_bf16(pfrag, vfr, oacc[nt], 0,0,0);
            }
        }

        __syncthreads();   // [D] V reads done -> kbuf reusable for K(t+4)

        if (t + 4 < ntiles) STAGE_K(t + 4);
    }
    #undef STAGE_K
    #undef STAGE_V

    // ---- 2-round tree merge of the 4 kv-parity partials (per qhalf) ----
    float* stme = (float*)(smem + STAT_AREA + w * 2048);

    __syncthreads();
    if (par & 1){    // par 1 -> slot qhalf ; par 3 -> slot 2+qhalf
        float* ox = (float*)(smem + ((par >> 1)*2 + qhalf) * KBUF);
        dump_partial(ox, stme, oacc, mrow, lrow, lane);
    }
    __syncthreads();
    if (!(par & 1)){
        const float* ox = (const float*)(smem + ((par >> 1)*2 + qhalf) * KBUF);
        const float* st = (const float*)(smem + STAT_AREA + (w + 2) * 2048);
        combine_partial(oacc, mrow, lrow, ox, st, lane);
    }
    __syncthreads();
    if (par == 2){
        float* ox = (float*)(smem + (2 + qhalf) * KBUF);
        dump_partial(ox, stme, oacc, mrow, lrow, lane);
    }
    __syncthreads();
    if (par == 0){
        const float* ox = (const float*)(smem + (2 + qhalf) * KBUF);
        const float* st = (const float*)(smem + STAT_AREA + (w + 4) * 2048);
        combine_partial(oacc, mrow, lrow, ox, st, lane);
        #pragma unroll
        for (int jj=0; jj<4; ++jj){
            const float inv = 1.0f / lrow[jj];
            float* orow = Og + ((size_t)(q0 + g*4 + jj) * BATCH + b) * DIM + c;
            #pragma unroll
            for (int nt=0; nt<32; ++nt) orow[nt*16] = oacc[nt][jj] * inv;
        }
    }
}

extern "C" void kernel_launch(void* const* d_in, const int* in_sizes, int n_in,
                              void* d_out, int out_size, void* d_ws, size_t ws_size,
                              hipStream_t stream)
{
    const float* Q = (const float*)d_in[0];
    const float* K = (const float*)d_in[1];
    const float* V = (const float*)d_in[2];
    const unsigned char* M = (const unsigned char*)d_in[3];
    float* O = (float*)d_out;
    (void)in_sizes; (void)n_in; (void)out_size; (void)ws_size;

    short* Kb = (short*)d_ws;                               // 8.4 MB swizzled K image
    short* Vt = Kb + (size_t)BATCH * SEQ * DIM;             // 8.4 MB linear V^T image

    conv_k<<<2048, 256, 0, stream>>>(K, Kb);
    conv_v<<<2048, 256, 0, stream>>>(V, Vt);

    hipFuncSetAttribute(reinterpret_cast<const void*>(fa_fwd),
                        hipFuncAttributeMaxDynamicSharedMemorySize, LDS_TOTAL);
    fa_fwd<<<256, 512, LDS_TOTAL, stream>>>(Q, Kb, Vt, M, O);
}